// Round 2
// baseline (812.536 us; speedup 1.0000x reference)
//
#include <hip/hip_runtime.h>
#include <math.h>

#define B   8
#define N   2048
#define DIN 2
#define DF  30
#define HH  64
#define KK  8
#define DATT 96          // DIN + DF + HH
#define CAP 384          // max connected cols per row (~102 avg, +15 sigma safe)
#define ALPHA 0.2f

__device__ __forceinline__ float lrelu(float x) { return x > 0.f ? x : ALPHA * x; }
__device__ __forceinline__ float elu1(float x)  { return x > 0.f ? x : (__expf(x) - 1.f); }

// ---------------------------------------------------------------------------
// Kernel B: bias_mat (0 / -1e9) -> padded ELL  (cols[i*CAP + e], cnt[i])
// one wave per row
// ---------------------------------------------------------------------------
__global__ void k_mask(const float* __restrict__ bias, int* __restrict__ cols,
                       int* __restrict__ cnt) {
    int i = blockIdx.x;
    int lane = threadIdx.x;
    int c = 0;
    for (int j0 = 0; j0 < N; j0 += 64) {
        float v = bias[(size_t)i * N + j0 + lane];
        bool conn = v > -1e8f;
        unsigned long long m = __ballot(conn);
        if (conn) {
            int pos = c + __popcll(m & ((1ull << lane) - 1ull));
            if (pos < CAP) cols[i * CAP + pos] = j0 + lane;
        }
        c += __popcll(m);
    }
    if (lane == 0) cnt[i] = c < CAP ? c : CAP;
}

// ---------------------------------------------------------------------------
// Kernel A: h = concat(inputs, envs, state); Wh[b,k,n,:] = h @ W_h[k];
// f1 = Wh . a1[k], f2 = Wh . a2[k].  Block: 256 thr, stages W_h[k] in LDS,
// 4 waves x 32 rows.  grid = (N/128, K, B)
// ---------------------------------------------------------------------------
__global__ void k_wh(const float* __restrict__ inp, const float* __restrict__ envs,
                     const float* __restrict__ st,  const float* __restrict__ W_h,
                     const float* __restrict__ a1,  const float* __restrict__ a2,
                     float* __restrict__ Wh, float* __restrict__ f1, float* __restrict__ f2) {
    int tile = blockIdx.x, k = blockIdx.y, b = blockIdx.z;
    int tid = threadIdx.x, lane = tid & 63, w = tid >> 6;
    __shared__ float Ws[DATT * HH];            // 24 KB
    const float* Wk = W_h + k * DATT * HH;
    for (int idx = tid * 4; idx < DATT * HH; idx += 1024)
        *(float4*)&Ws[idx] = *(const float4*)&Wk[idx];
    __syncthreads();
    float a1k = a1[k * HH + lane], a2k = a2[k * HH + lane];
    int bkN = (b * KK + k) * N;
    for (int rr = 0; rr < 32; ++rr) {
        int n = tile * 128 + w * 32 + rr;
        const float* ip = inp  + (size_t)(b * N + n) * DIN;
        const float* ep = envs + (size_t)(b * N + n) * DF;
        const float* sp = st   + (size_t)(b * N + n) * HH;
        float acc = 0.f;
#pragma unroll
        for (int d = 0; d < DIN; ++d) acc += ip[d] * Ws[d * HH + lane];
#pragma unroll
        for (int d = 0; d < DF; ++d)  acc += ep[d] * Ws[(DIN + d) * HH + lane];
#pragma unroll
        for (int d = 0; d < HH; ++d)  acc += sp[d] * Ws[(DIN + DF + d) * HH + lane];
        Wh[(size_t)(bkN + n) * HH + lane] = acc;
        float p1 = acc * a1k, p2 = acc * a2k;
#pragma unroll
        for (int off = 32; off; off >>= 1) {
            p1 += __shfl_down(p1, off);
            p2 += __shfl_down(p2, off);
        }
        if (lane == 0) { f1[bkN + n] = p1; f2[bkN + n] = p2; }
    }
}

// ---------------------------------------------------------------------------
// Kernel C: sparse masked softmax-attention, multihead.
// One wave per (b,k,row).  lane = output channel h.
// h1[b,n,k*H+h] = elu( (att @ Wh)[...] )
// grid = (N/4, B*K), block 256
// ---------------------------------------------------------------------------
__global__ void k_attn(const float* __restrict__ Wh, const float* __restrict__ f1,
                       const float* __restrict__ f2, const int* __restrict__ cols,
                       const int* __restrict__ cnt, float* __restrict__ h1) {
    int bk = blockIdx.y;
    int b = bk >> 3, k = bk & 7;
    int w = threadIdx.x >> 6, lane = threadIdx.x & 63;
    int i = blockIdx.x * 4 + w;
    int c = cnt[i];
    const int*   cl  = cols + i * CAP;
    const float* f2p = f2 + bk * N;
    const float* Whp = Wh + (size_t)bk * N * HH;
    float f1i = f1[bk * N + i];

    // pass 1: row max over connected cols
    float m = -1e30f;
    for (int e = lane; e < c; e += 64) {
        int j = cl[e];
        m = fmaxf(m, lrelu(f1i + f2p[j]));
    }
#pragma unroll
    for (int off = 32; off; off >>= 1) m = fmaxf(m, __shfl_xor(m, off));

    // pass 2: Z and weighted sum of Wh rows (lane = h)
    float Z = 0.f, acc = 0.f;
    int e = 0;
    for (; e + 4 <= c; e += 4) {
        int j0 = cl[e], j1 = cl[e + 1], j2 = cl[e + 2], j3 = cl[e + 3];
        float w0 = __expf(lrelu(f1i + f2p[j0]) - m);
        float w1 = __expf(lrelu(f1i + f2p[j1]) - m);
        float w2 = __expf(lrelu(f1i + f2p[j2]) - m);
        float w3 = __expf(lrelu(f1i + f2p[j3]) - m);
        Z += (w0 + w1) + (w2 + w3);
        acc += w0 * Whp[(size_t)j0 * HH + lane];
        acc += w1 * Whp[(size_t)j1 * HH + lane];
        acc += w2 * Whp[(size_t)j2 * HH + lane];
        acc += w3 * Whp[(size_t)j3 * HH + lane];
    }
    for (; e < c; ++e) {
        int j = cl[e];
        float ww = __expf(lrelu(f1i + f2p[j]) - m);
        Z += ww;
        acc += ww * Whp[(size_t)j * HH + lane];
    }
    float v = acc / Z;
    h1[(size_t)(b * N + i) * (KK * HH) + k * HH + lane] = elu1(v);
}

// ---------------------------------------------------------------------------
// Kernel D: Wh_o = h1 @ W_o  (512 -> 64), f1_o, f2_o.
// Block 256 thr handles 64 rows; W_o staged in 4 x 32KB LDS phases.
// grid = B*N/64 = 256
// ---------------------------------------------------------------------------
__global__ void k_who(const float* __restrict__ h1, const float* __restrict__ W_o,
                      const float* __restrict__ a1o, const float* __restrict__ a2o,
                      float* __restrict__ Who, float* __restrict__ f1o,
                      float* __restrict__ f2o) {
    __shared__ float Ws[128 * HH];             // 32 KB
    int tid = threadIdx.x, lane = tid & 63, w = tid >> 6;
    int row0 = blockIdx.x * 64;
    float acc[16];
#pragma unroll
    for (int r = 0; r < 16; ++r) acc[r] = 0.f;
    for (int ph = 0; ph < 4; ++ph) {
        __syncthreads();
        for (int idx = tid * 4; idx < 128 * HH; idx += 1024)
            *(float4*)&Ws[idx] = *(const float4*)&W_o[ph * 128 * HH + idx];
        __syncthreads();
        for (int r = 0; r < 16; ++r) {
            int row = row0 + w * 16 + r;
            const float* hp = h1 + (size_t)row * (KK * HH) + ph * 128;
            float a = acc[r];
#pragma unroll 8
            for (int d = 0; d < 128; ++d) a += hp[d] * Ws[d * HH + lane];
            acc[r] = a;
        }
    }
    float a1l = a1o[lane], a2l = a2o[lane];
    for (int r = 0; r < 16; ++r) {
        int row = row0 + w * 16 + r;
        Who[(size_t)row * HH + lane] = acc[r];
        float p1 = acc[r] * a1l, p2 = acc[r] * a2l;
#pragma unroll
        for (int off = 32; off; off >>= 1) {
            p1 += __shfl_down(p1, off);
            p2 += __shfl_down(p2, off);
        }
        if (lane == 0) { f1o[row] = p1; f2o[row] = p2; }
    }
}

// ---------------------------------------------------------------------------
// Kernel E: second sparse attention + final elu -> out
// grid = (N/4, B), block 256
// ---------------------------------------------------------------------------
__global__ void k_attn2(const float* __restrict__ Who, const float* __restrict__ f1o,
                        const float* __restrict__ f2o, const int* __restrict__ cols,
                        const int* __restrict__ cnt, float* __restrict__ out) {
    int b = blockIdx.y;
    int w = threadIdx.x >> 6, lane = threadIdx.x & 63;
    int i = blockIdx.x * 4 + w;
    int c = cnt[i];
    const int*   cl  = cols + i * CAP;
    const float* f2p = f2o + b * N;
    const float* Wp  = Who + (size_t)b * N * HH;
    float f1i = f1o[b * N + i];

    float m = -1e30f;
    for (int e = lane; e < c; e += 64) {
        int j = cl[e];
        m = fmaxf(m, lrelu(f1i + f2p[j]));
    }
#pragma unroll
    for (int off = 32; off; off >>= 1) m = fmaxf(m, __shfl_xor(m, off));

    float Z = 0.f, acc = 0.f;
    int e = 0;
    for (; e + 4 <= c; e += 4) {
        int j0 = cl[e], j1 = cl[e + 1], j2 = cl[e + 2], j3 = cl[e + 3];
        float w0 = __expf(lrelu(f1i + f2p[j0]) - m);
        float w1 = __expf(lrelu(f1i + f2p[j1]) - m);
        float w2 = __expf(lrelu(f1i + f2p[j2]) - m);
        float w3 = __expf(lrelu(f1i + f2p[j3]) - m);
        Z += (w0 + w1) + (w2 + w3);
        acc += w0 * Wp[(size_t)j0 * HH + lane];
        acc += w1 * Wp[(size_t)j1 * HH + lane];
        acc += w2 * Wp[(size_t)j2 * HH + lane];
        acc += w3 * Wp[(size_t)j3 * HH + lane];
    }
    for (; e < c; ++e) {
        int j = cl[e];
        float ww = __expf(lrelu(f1i + f2p[j]) - m);
        Z += ww;
        acc += ww * Wp[(size_t)j * HH + lane];
    }
    out[(size_t)(b * N + i) * HH + lane] = elu1(acc / Z);
}

// ---------------------------------------------------------------------------
extern "C" void kernel_launch(void* const* d_in, const int* in_sizes, int n_in,
                              void* d_out, int out_size, void* d_ws, size_t ws_size,
                              hipStream_t stream) {
    const float* inp   = (const float*)d_in[0];
    const float* envs  = (const float*)d_in[1];
    const float* st    = (const float*)d_in[2];
    const float* bias  = (const float*)d_in[3];
    const float* W_h   = (const float*)d_in[4];
    const float* a1_h  = (const float*)d_in[5];
    const float* a2_h  = (const float*)d_in[6];
    const float* W_o   = (const float*)d_in[7];
    const float* a1_o  = (const float*)d_in[8];
    const float* a2_o  = (const float*)d_in[9];
    float* out = (float*)d_out;

    char* ws = (char*)d_ws;
    size_t off = 0;
    float* Wh  = (float*)(ws + off); off += (size_t)B * KK * N * HH * 4;   // 33.5 MB
    float* f1  = (float*)(ws + off); off += (size_t)B * KK * N * 4;        // 0.5 MB
    float* f2  = (float*)(ws + off); off += (size_t)B * KK * N * 4;        // 0.5 MB
    float* h1  = (float*)(ws + off); off += (size_t)B * N * KK * HH * 4;   // 33.5 MB
    float* Who = (float*)(ws + off); off += (size_t)B * N * HH * 4;        // 4 MB
    float* f1o = (float*)(ws + off); off += (size_t)B * N * 4;
    float* f2o = (float*)(ws + off); off += (size_t)B * N * 4;
    int*   cols = (int*)(ws + off);  off += (size_t)N * CAP * 4;           // 3 MB
    int*   cnt  = (int*)(ws + off);  off += (size_t)N * 4;

    // ELL mask (independent of everything else)
    k_mask<<<dim3(N), dim3(64), 0, stream>>>(bias, cols, cnt);
    // per-head projections
    k_wh<<<dim3(N / 128, KK, B), dim3(256), 0, stream>>>(inp, envs, st, W_h, a1_h, a2_h,
                                                         Wh, f1, f2);
    // multihead sparse attention -> h1
    k_attn<<<dim3(N / 4, B * KK), dim3(256), 0, stream>>>(Wh, f1, f2, cols, cnt, h1);
    // output projection
    k_who<<<dim3(B * N / 64), dim3(256), 0, stream>>>(h1, W_o, a1_o, a2_o, Who, f1o, f2o);
    // final sparse attention + elu
    k_attn2<<<dim3(N / 4, B), dim3(256), 0, stream>>>(Who, f1o, f2o, cols, cnt, out);
}

// Round 3
// 585.918 us; speedup vs baseline: 1.3868x; 1.3868x over previous
//
#include <hip/hip_runtime.h>
#include <math.h>

#define B   8
#define N   2048
#define DIN 2
#define DF  30
#define HH  64
#define KK  8
#define DATT 96          // DIN + DF + HH
#define CAP 384          // global ELL cap (~103 avg, huge margin)
#define CAPL 176         // LDS edge cap (binom(2048,.05) max ~140; P(>176) ~ e^-40)
#define ALPHA 0.2f

__device__ __forceinline__ float lrelu(float x) { return x > 0.f ? x : ALPHA * x; }
__device__ __forceinline__ float elu1(float x)  { return x > 0.f ? x : (__expf(x) - 1.f); }

// ---------------------------------------------------------------------------
// Kernel B: bias_mat (0 / -1e9) -> padded ELL  (cols[i*CAP + e], cnt[i])
// one wave per row
// ---------------------------------------------------------------------------
__global__ void k_mask(const float* __restrict__ bias, int* __restrict__ cols,
                       int* __restrict__ cnt) {
    int i = blockIdx.x;
    int lane = threadIdx.x;
    int c = 0;
    for (int j0 = 0; j0 < N; j0 += 64) {
        float v = bias[(size_t)i * N + j0 + lane];
        bool conn = v > -1e8f;
        unsigned long long m = __ballot(conn);
        if (conn) {
            int pos = c + __popcll(m & ((1ull << lane) - 1ull));
            if (pos < CAP) cols[i * CAP + pos] = j0 + lane;
        }
        c += __popcll(m);
    }
    if (lane == 0) cnt[i] = c < CAP ? c : CAP;
}

// ---------------------------------------------------------------------------
// Kernel A: h = concat(inputs, envs, state); Wh[b,k,n,:] = h @ W_h[k];
// f1 = Wh . a1[k], f2 = Wh . a2[k].
// ---------------------------------------------------------------------------
__global__ void k_wh(const float* __restrict__ inp, const float* __restrict__ envs,
                     const float* __restrict__ st,  const float* __restrict__ W_h,
                     const float* __restrict__ a1,  const float* __restrict__ a2,
                     float* __restrict__ Wh, float* __restrict__ f1, float* __restrict__ f2) {
    int tile = blockIdx.x, k = blockIdx.y, b = blockIdx.z;
    int tid = threadIdx.x, lane = tid & 63, w = tid >> 6;
    __shared__ float Ws[DATT * HH];            // 24 KB
    const float* Wk = W_h + k * DATT * HH;
    for (int idx = tid * 4; idx < DATT * HH; idx += 1024)
        *(float4*)&Ws[idx] = *(const float4*)&Wk[idx];
    __syncthreads();
    float a1k = a1[k * HH + lane], a2k = a2[k * HH + lane];
    int bkN = (b * KK + k) * N;
    for (int rr = 0; rr < 32; ++rr) {
        int n = tile * 128 + w * 32 + rr;
        const float* ip = inp  + (size_t)(b * N + n) * DIN;
        const float* ep = envs + (size_t)(b * N + n) * DF;
        const float* sp = st   + (size_t)(b * N + n) * HH;
        float acc = 0.f;
#pragma unroll
        for (int d = 0; d < DIN; ++d) acc += ip[d] * Ws[d * HH + lane];
#pragma unroll
        for (int d = 0; d < DF; ++d)  acc += ep[d] * Ws[(DIN + d) * HH + lane];
#pragma unroll
        for (int d = 0; d < HH; ++d)  acc += sp[d] * Ws[(DIN + DF + d) * HH + lane];
        Wh[(size_t)(bkN + n) * HH + lane] = acc;
        float p1 = acc * a1k, p2 = acc * a2k;
#pragma unroll
        for (int off = 32; off; off >>= 1) {
            p1 += __shfl_down(p1, off);
            p2 += __shfl_down(p2, off);
        }
        if (lane == 0) { f1[bkN + n] = p1; f2[bkN + n] = p2; }
    }
}

// ---------------------------------------------------------------------------
// Kernel C v2: sparse masked softmax-attention, multihead.
// Block 256 thr = 4 waves; 16 rows/block (4 rows per wave, one per 16-lane
// group, 4 channels per lane).  f2[bk] staged in LDS; per-row edge
// (byte-offset, weight) pairs staged in LDS.
// grid = (N/16, B*K)
// ---------------------------------------------------------------------------
__global__ void k_attn(const float* __restrict__ Wh, const float* __restrict__ f1,
                       const float* __restrict__ f2, const int* __restrict__ cols,
                       const int* __restrict__ cnt, float* __restrict__ h1) {
    __shared__ float  f2s[N];                  // 8 KB
    __shared__ float2 sedge[16][CAPL + 2];     // ~22.3 KB (pad 2 -> group-conflict-free)
    int bk = blockIdx.y;
    int b = bk >> 3, k = bk & 7;
    int tid = threadIdx.x;
    int lane = tid & 63, w = tid >> 6;
    int g = lane >> 4, sub = lane & 15;
    int r = w * 4 + g;
    int i = blockIdx.x * 16 + r;

    const float* f2p = f2 + bk * N;
    for (int idx = tid * 4; idx < N; idx += 1024)
        *(float4*)&f2s[idx] = *(const float4*)&f2p[idx];
    __syncthreads();

    int c = cnt[i]; if (c > CAPL) c = CAPL;
    float f1i = f1[bk * N + i];
    const int* cl = cols + i * CAP;

    // pass A: scores + byte offsets into LDS, row max (16-lane parallel)
    float m = -1e30f;
    for (int e = sub; e < c; e += 16) {
        int j = cl[e];
        float s = lrelu(f1i + f2s[j]);
        sedge[r][e] = make_float2(__int_as_float(j << 8), s);
        m = fmaxf(m, s);
    }
#pragma unroll
    for (int off = 8; off; off >>= 1) m = fmaxf(m, __shfl_xor(m, off));

    // pass B: exp + Z (16-lane parallel)
    float Z = 0.f;
    for (int e = sub; e < c; e += 16) {
        float wt = __expf(sedge[r][e].y - m);
        sedge[r][e].y = wt;
        Z += wt;
    }
#pragma unroll
    for (int off = 8; off; off >>= 1) Z += __shfl_xor(Z, off);
    float invZ = 1.f / Z;

    // pass C: serial gather-FMA, 4 channels/lane, 4 rows per wave
    const char* Whp = (const char*)(Wh + (size_t)bk * N * HH);
    int lane4 = sub << 4;
    float4 acc = make_float4(0.f, 0.f, 0.f, 0.f);
    int e = 0;
    for (; e + 2 <= c; e += 2) {
        float2 p0 = sedge[r][e];
        float2 p1 = sedge[r][e + 1];
        float4 v0 = *(const float4*)(Whp + (__float_as_int(p0.x) + lane4));
        float4 v1 = *(const float4*)(Whp + (__float_as_int(p1.x) + lane4));
        acc.x += p0.y * v0.x; acc.y += p0.y * v0.y;
        acc.z += p0.y * v0.z; acc.w += p0.y * v0.w;
        acc.x += p1.y * v1.x; acc.y += p1.y * v1.y;
        acc.z += p1.y * v1.z; acc.w += p1.y * v1.w;
    }
    if (e < c) {
        float2 p0 = sedge[r][e];
        float4 v0 = *(const float4*)(Whp + (__float_as_int(p0.x) + lane4));
        acc.x += p0.y * v0.x; acc.y += p0.y * v0.y;
        acc.z += p0.y * v0.z; acc.w += p0.y * v0.w;
    }
    float4 o;
    o.x = elu1(acc.x * invZ); o.y = elu1(acc.y * invZ);
    o.z = elu1(acc.z * invZ); o.w = elu1(acc.w * invZ);
    *(float4*)&h1[(size_t)(b * N + i) * (KK * HH) + k * HH + sub * 4] = o;
}

// ---------------------------------------------------------------------------
// Kernel D: Wh_o = h1 @ W_o  (512 -> 64), f1_o, f2_o.
// ---------------------------------------------------------------------------
__global__ void k_who(const float* __restrict__ h1, const float* __restrict__ W_o,
                      const float* __restrict__ a1o, const float* __restrict__ a2o,
                      float* __restrict__ Who, float* __restrict__ f1o,
                      float* __restrict__ f2o) {
    __shared__ float Ws[128 * HH];             // 32 KB
    int tid = threadIdx.x, lane = tid & 63, w = tid >> 6;
    int row0 = blockIdx.x * 64;
    float acc[16];
#pragma unroll
    for (int r = 0; r < 16; ++r) acc[r] = 0.f;
    for (int ph = 0; ph < 4; ++ph) {
        __syncthreads();
        for (int idx = tid * 4; idx < 128 * HH; idx += 1024)
            *(float4*)&Ws[idx] = *(const float4*)&W_o[ph * 128 * HH + idx];
        __syncthreads();
        for (int r = 0; r < 16; ++r) {
            int row = row0 + w * 16 + r;
            const float* hp = h1 + (size_t)row * (KK * HH) + ph * 128;
            float a = acc[r];
#pragma unroll 8
            for (int d = 0; d < 128; ++d) a += hp[d] * Ws[d * HH + lane];
            acc[r] = a;
        }
    }
    float a1l = a1o[lane], a2l = a2o[lane];
    for (int r = 0; r < 16; ++r) {
        int row = row0 + w * 16 + r;
        Who[(size_t)row * HH + lane] = acc[r];
        float p1 = acc[r] * a1l, p2 = acc[r] * a2l;
#pragma unroll
        for (int off = 32; off; off >>= 1) {
            p1 += __shfl_down(p1, off);
            p2 += __shfl_down(p2, off);
        }
        if (lane == 0) { f1o[row] = p1; f2o[row] = p2; }
    }
}

// ---------------------------------------------------------------------------
// Kernel E v2: second sparse attention + final elu -> out (same structure as
// k_attn v2, single head-group).  grid = (N/16, B)
// ---------------------------------------------------------------------------
__global__ void k_attn2(const float* __restrict__ Who, const float* __restrict__ f1o,
                        const float* __restrict__ f2o, const int* __restrict__ cols,
                        const int* __restrict__ cnt, float* __restrict__ out) {
    __shared__ float  f2s[N];
    __shared__ float2 sedge[16][CAPL + 2];
    int b = blockIdx.y;
    int tid = threadIdx.x;
    int lane = tid & 63, w = tid >> 6;
    int g = lane >> 4, sub = lane & 15;
    int r = w * 4 + g;
    int i = blockIdx.x * 16 + r;

    const float* f2p = f2o + b * N;
    for (int idx = tid * 4; idx < N; idx += 1024)
        *(float4*)&f2s[idx] = *(const float4*)&f2p[idx];
    __syncthreads();

    int c = cnt[i]; if (c > CAPL) c = CAPL;
    float f1i = f1o[b * N + i];
    const int* cl = cols + i * CAP;

    float m = -1e30f;
    for (int e = sub; e < c; e += 16) {
        int j = cl[e];
        float s = lrelu(f1i + f2s[j]);
        sedge[r][e] = make_float2(__int_as_float(j << 8), s);
        m = fmaxf(m, s);
    }
#pragma unroll
    for (int off = 8; off; off >>= 1) m = fmaxf(m, __shfl_xor(m, off));

    float Z = 0.f;
    for (int e = sub; e < c; e += 16) {
        float wt = __expf(sedge[r][e].y - m);
        sedge[r][e].y = wt;
        Z += wt;
    }
#pragma unroll
    for (int off = 8; off; off >>= 1) Z += __shfl_xor(Z, off);
    float invZ = 1.f / Z;

    const char* Wp = (const char*)(Who + (size_t)b * N * HH);
    int lane4 = sub << 4;
    float4 acc = make_float4(0.f, 0.f, 0.f, 0.f);
    int e = 0;
    for (; e + 2 <= c; e += 2) {
        float2 p0 = sedge[r][e];
        float2 p1 = sedge[r][e + 1];
        float4 v0 = *(const float4*)(Wp + (__float_as_int(p0.x) + lane4));
        float4 v1 = *(const float4*)(Wp + (__float_as_int(p1.x) + lane4));
        acc.x += p0.y * v0.x; acc.y += p0.y * v0.y;
        acc.z += p0.y * v0.z; acc.w += p0.y * v0.w;
        acc.x += p1.y * v1.x; acc.y += p1.y * v1.y;
        acc.z += p1.y * v1.z; acc.w += p1.y * v1.w;
    }
    if (e < c) {
        float2 p0 = sedge[r][e];
        float4 v0 = *(const float4*)(Wp + (__float_as_int(p0.x) + lane4));
        acc.x += p0.y * v0.x; acc.y += p0.y * v0.y;
        acc.z += p0.y * v0.z; acc.w += p0.y * v0.w;
    }
    float4 o;
    o.x = elu1(acc.x * invZ); o.y = elu1(acc.y * invZ);
    o.z = elu1(acc.z * invZ); o.w = elu1(acc.w * invZ);
    *(float4*)&out[(size_t)(b * N + i) * HH + sub * 4] = o;
}

// ---------------------------------------------------------------------------
extern "C" void kernel_launch(void* const* d_in, const int* in_sizes, int n_in,
                              void* d_out, int out_size, void* d_ws, size_t ws_size,
                              hipStream_t stream) {
    const float* inp   = (const float*)d_in[0];
    const float* envs  = (const float*)d_in[1];
    const float* st    = (const float*)d_in[2];
    const float* bias  = (const float*)d_in[3];
    const float* W_h   = (const float*)d_in[4];
    const float* a1_h  = (const float*)d_in[5];
    const float* a2_h  = (const float*)d_in[6];
    const float* W_o   = (const float*)d_in[7];
    const float* a1_o  = (const float*)d_in[8];
    const float* a2_o  = (const float*)d_in[9];
    float* out = (float*)d_out;

    char* ws = (char*)d_ws;
    size_t off = 0;
    float* Wh  = (float*)(ws + off); off += (size_t)B * KK * N * HH * 4;   // 33.5 MB
    float* f1  = (float*)(ws + off); off += (size_t)B * KK * N * 4;        // 0.5 MB
    float* f2  = (float*)(ws + off); off += (size_t)B * KK * N * 4;        // 0.5 MB
    float* h1  = (float*)(ws + off); off += (size_t)B * N * KK * HH * 4;   // 33.5 MB
    float* Who = (float*)(ws + off); off += (size_t)B * N * HH * 4;        // 4 MB
    float* f1o = (float*)(ws + off); off += (size_t)B * N * 4;
    float* f2o = (float*)(ws + off); off += (size_t)B * N * 4;
    int*   cols = (int*)(ws + off);  off += (size_t)N * CAP * 4;           // 3 MB
    int*   cnt  = (int*)(ws + off);  off += (size_t)N * 4;

    k_mask<<<dim3(N), dim3(64), 0, stream>>>(bias, cols, cnt);
    k_wh<<<dim3(N / 128, KK, B), dim3(256), 0, stream>>>(inp, envs, st, W_h, a1_h, a2_h,
                                                         Wh, f1, f2);
    k_attn<<<dim3(N / 16, B * KK), dim3(256), 0, stream>>>(Wh, f1, f2, cols, cnt, h1);
    k_who<<<dim3(B * N / 64), dim3(256), 0, stream>>>(h1, W_o, a1_o, a2_o, Who, f1o, f2o);
    k_attn2<<<dim3(N / 16, B), dim3(256), 0, stream>>>(Who, f1o, f2o, cols, cnt, out);
}

// Round 4
// 440.272 us; speedup vs baseline: 1.8455x; 1.3308x over previous
//
#include <hip/hip_runtime.h>
#include <hip/hip_bf16.h>
#include <math.h>

#define B   8
#define N   2048
#define DIN 2
#define DF  30
#define HH  64
#define KK  8
#define DATT 96          // DIN + DF + HH
#define CAP 384          // global ELL cap (~103 avg, huge margin)
#define CAPL 176         // LDS edge cap (binom(2048,.05) max ~140; P(>176) ~ e^-40)
#define ALPHA 0.2f

__device__ __forceinline__ float lrelu(float x) { return x > 0.f ? x : ALPHA * x; }
__device__ __forceinline__ float elu1(float x)  { return x > 0.f ? x : (__expf(x) - 1.f); }

// ---------------------------------------------------------------------------
// Kernel B: bias_mat (0 / -1e9) -> padded ELL  (cols[i*CAP + e], cnt[i])
// ---------------------------------------------------------------------------
__global__ void k_mask(const float* __restrict__ bias, int* __restrict__ cols,
                       int* __restrict__ cnt) {
    int i = blockIdx.x;
    int lane = threadIdx.x;
    int c = 0;
    for (int j0 = 0; j0 < N; j0 += 64) {
        float v = bias[(size_t)i * N + j0 + lane];
        bool conn = v > -1e8f;
        unsigned long long m = __ballot(conn);
        if (conn) {
            int pos = c + __popcll(m & ((1ull << lane) - 1ull));
            if (pos < CAP) cols[i * CAP + pos] = j0 + lane;
        }
        c += __popcll(m);
    }
    if (lane == 0) cnt[i] = c < CAP ? c : CAP;
}

// ---------------------------------------------------------------------------
// Kernel A: Whb (bf16) = h @ W_h[k];  f1/f2 in f32.
// grid = (N/128, K, B), block 256
// ---------------------------------------------------------------------------
__global__ void k_wh(const float* __restrict__ inp, const float* __restrict__ envs,
                     const float* __restrict__ st,  const float* __restrict__ W_h,
                     const float* __restrict__ a1,  const float* __restrict__ a2,
                     __hip_bfloat16* __restrict__ Whb,
                     float* __restrict__ f1, float* __restrict__ f2) {
    int tile = blockIdx.x, k = blockIdx.y, b = blockIdx.z;
    int tid = threadIdx.x, lane = tid & 63, w = tid >> 6;
    __shared__ float Ws[DATT * HH];            // 24 KB
    const float* Wk = W_h + k * DATT * HH;
    for (int idx = tid * 4; idx < DATT * HH; idx += 1024)
        *(float4*)&Ws[idx] = *(const float4*)&Wk[idx];
    __syncthreads();
    float a1k = a1[k * HH + lane], a2k = a2[k * HH + lane];
    int bkN = (b * KK + k) * N;
    for (int rr = 0; rr < 32; ++rr) {
        int n = tile * 128 + w * 32 + rr;
        const float* ip = inp  + (size_t)(b * N + n) * DIN;
        const float* ep = envs + (size_t)(b * N + n) * DF;
        const float* sp = st   + (size_t)(b * N + n) * HH;
        float acc = 0.f;
#pragma unroll
        for (int d = 0; d < DIN; ++d) acc += ip[d] * Ws[d * HH + lane];
#pragma unroll
        for (int d = 0; d < DF; ++d)  acc += ep[d] * Ws[(DIN + d) * HH + lane];
#pragma unroll
        for (int d = 0; d < HH; ++d)  acc += sp[d] * Ws[(DIN + DF + d) * HH + lane];
        Whb[(size_t)(bkN + n) * HH + lane] = __float2bfloat16(acc);
        float p1 = acc * a1k, p2 = acc * a2k;
#pragma unroll
        for (int off = 32; off; off >>= 1) {
            p1 += __shfl_down(p1, off);
            p2 += __shfl_down(p2, off);
        }
        if (lane == 0) { f1[bkN + n] = p1; f2[bkN + n] = p2; }
    }
}

// ---------------------------------------------------------------------------
// Kernel C: sparse softmax-attention, multihead.  bf16 Wh gather (128 B rows).
// 16 rows/block, 4 rows/wave (16-lane groups, 4 ch/lane).
// grid = (N/16, B*K), block 256
// ---------------------------------------------------------------------------
__global__ void k_attn(const __hip_bfloat16* __restrict__ Whb, const float* __restrict__ f1,
                       const float* __restrict__ f2, const int* __restrict__ cols,
                       const int* __restrict__ cnt, float* __restrict__ h1) {
    __shared__ float  f2s[N];                  // 8 KB
    __shared__ float2 sedge[16][CAPL + 2];     // ~22.3 KB
    int bk = blockIdx.y;
    int b = bk >> 3, k = bk & 7;
    int tid = threadIdx.x;
    int lane = tid & 63, w = tid >> 6;
    int g = lane >> 4, sub = lane & 15;
    int r = w * 4 + g;
    int i = blockIdx.x * 16 + r;

    const float* f2p = f2 + bk * N;
    for (int idx = tid * 4; idx < N; idx += 1024)
        *(float4*)&f2s[idx] = *(const float4*)&f2p[idx];
    __syncthreads();

    int c = cnt[i]; if (c > CAPL) c = CAPL;
    float f1i = f1[bk * N + i];
    const int* cl = cols + i * CAP;

    // pass A: scores + byte offsets (row stride 128 B), row max
    float m = -1e30f;
    for (int e = sub; e < c; e += 16) {
        int j = cl[e];
        float s = lrelu(f1i + f2s[j]);
        sedge[r][e] = make_float2(__int_as_float(j << 7), s);
        m = fmaxf(m, s);
    }
#pragma unroll
    for (int off = 8; off; off >>= 1) m = fmaxf(m, __shfl_xor(m, off));

    // pass B: exp + Z
    float Z = 0.f;
    for (int e = sub; e < c; e += 16) {
        float wt = __expf(sedge[r][e].y - m);
        sedge[r][e].y = wt;
        Z += wt;
    }
#pragma unroll
    for (int off = 8; off; off >>= 1) Z += __shfl_xor(Z, off);
    float invZ = 1.f / Z;

    // pass C: gather-FMA, bf16 rows, 4 channels/lane (8 B loads)
    const char* Whp = (const char*)(Whb + (size_t)bk * N * HH);
    int lane8 = sub << 3;
    float4 acc = make_float4(0.f, 0.f, 0.f, 0.f);
    int e = 0;
    for (; e + 2 <= c; e += 2) {
        float2 p0 = sedge[r][e];
        float2 p1 = sedge[r][e + 1];
        uint2 v0 = *(const uint2*)(Whp + (__float_as_int(p0.x) + lane8));
        uint2 v1 = *(const uint2*)(Whp + (__float_as_int(p1.x) + lane8));
        acc.x += p0.y * __int_as_float(v0.x << 16);
        acc.y += p0.y * __int_as_float(v0.x & 0xffff0000u);
        acc.z += p0.y * __int_as_float(v0.y << 16);
        acc.w += p0.y * __int_as_float(v0.y & 0xffff0000u);
        acc.x += p1.y * __int_as_float(v1.x << 16);
        acc.y += p1.y * __int_as_float(v1.x & 0xffff0000u);
        acc.z += p1.y * __int_as_float(v1.y << 16);
        acc.w += p1.y * __int_as_float(v1.y & 0xffff0000u);
    }
    if (e < c) {
        float2 p0 = sedge[r][e];
        uint2 v0 = *(const uint2*)(Whp + (__float_as_int(p0.x) + lane8));
        acc.x += p0.y * __int_as_float(v0.x << 16);
        acc.y += p0.y * __int_as_float(v0.x & 0xffff0000u);
        acc.z += p0.y * __int_as_float(v0.y << 16);
        acc.w += p0.y * __int_as_float(v0.y & 0xffff0000u);
    }
    float4 o;
    o.x = elu1(acc.x * invZ); o.y = elu1(acc.y * invZ);
    o.z = elu1(acc.z * invZ); o.w = elu1(acc.w * invZ);
    *(float4*)&h1[(size_t)(b * N + i) * (KK * HH) + k * HH + sub * 4] = o;
}

// ---------------------------------------------------------------------------
// Kernel D v2: Who = h1 @ W_o (512 -> 64) + f1o/f2o.
// 1024 blocks, 16 rows/block, 4 rows/wave (16-lane groups, float4 acc/lane),
// W_o staged in 4 x 32KB LDS phases.
// ---------------------------------------------------------------------------
__global__ void k_who(const float* __restrict__ h1, const float* __restrict__ W_o,
                      const float* __restrict__ a1o, const float* __restrict__ a2o,
                      float* __restrict__ Who, float* __restrict__ f1o,
                      float* __restrict__ f2o) {
    __shared__ float Ws[128 * HH];             // 32 KB
    int tid = threadIdx.x, lane = tid & 63, w = tid >> 6;
    int g = lane >> 4, sub = lane & 15;
    int row = blockIdx.x * 16 + w * 4 + g;
    const float* hp = h1 + (size_t)row * (KK * HH);
    float4 acc = make_float4(0.f, 0.f, 0.f, 0.f);
    for (int ph = 0; ph < 4; ++ph) {
        __syncthreads();
        for (int idx = tid * 4; idx < 128 * HH; idx += 1024)
            *(float4*)&Ws[idx] = *(const float4*)&W_o[ph * 128 * HH + idx];
        __syncthreads();
#pragma unroll 4
        for (int d0 = 0; d0 < 128; d0 += 4) {
            float4 hv = *(const float4*)(hp + ph * 128 + d0);
#pragma unroll
            for (int dd = 0; dd < 4; ++dd) {
                float hs = dd == 0 ? hv.x : dd == 1 ? hv.y : dd == 2 ? hv.z : hv.w;
                float4 wv = *(const float4*)&Ws[(d0 + dd) * HH + sub * 4];
                acc.x += hs * wv.x; acc.y += hs * wv.y;
                acc.z += hs * wv.z; acc.w += hs * wv.w;
            }
        }
    }
    *(float4*)&Who[(size_t)row * HH + sub * 4] = acc;
    float4 a1v = *(const float4*)&a1o[sub * 4];
    float4 a2v = *(const float4*)&a2o[sub * 4];
    float p1 = acc.x * a1v.x + acc.y * a1v.y + acc.z * a1v.z + acc.w * a1v.w;
    float p2 = acc.x * a2v.x + acc.y * a2v.y + acc.z * a2v.z + acc.w * a2v.w;
#pragma unroll
    for (int off = 8; off; off >>= 1) {
        p1 += __shfl_xor(p1, off);
        p2 += __shfl_xor(p2, off);
    }
    if (sub == 0) { f1o[row] = p1; f2o[row] = p2; }
}

// ---------------------------------------------------------------------------
// Kernel E: second sparse attention + final elu -> out (f32 Who gather)
// grid = (N/16, B), block 256
// ---------------------------------------------------------------------------
__global__ void k_attn2(const float* __restrict__ Who, const float* __restrict__ f1o,
                        const float* __restrict__ f2o, const int* __restrict__ cols,
                        const int* __restrict__ cnt, float* __restrict__ out) {
    __shared__ float  f2s[N];
    __shared__ float2 sedge[16][CAPL + 2];
    int b = blockIdx.y;
    int tid = threadIdx.x;
    int lane = tid & 63, w = tid >> 6;
    int g = lane >> 4, sub = lane & 15;
    int r = w * 4 + g;
    int i = blockIdx.x * 16 + r;

    const float* f2p = f2o + b * N;
    for (int idx = tid * 4; idx < N; idx += 1024)
        *(float4*)&f2s[idx] = *(const float4*)&f2p[idx];
    __syncthreads();

    int c = cnt[i]; if (c > CAPL) c = CAPL;
    float f1i = f1o[b * N + i];
    const int* cl = cols + i * CAP;

    float m = -1e30f;
    for (int e = sub; e < c; e += 16) {
        int j = cl[e];
        float s = lrelu(f1i + f2s[j]);
        sedge[r][e] = make_float2(__int_as_float(j << 8), s);
        m = fmaxf(m, s);
    }
#pragma unroll
    for (int off = 8; off; off >>= 1) m = fmaxf(m, __shfl_xor(m, off));

    float Z = 0.f;
    for (int e = sub; e < c; e += 16) {
        float wt = __expf(sedge[r][e].y - m);
        sedge[r][e].y = wt;
        Z += wt;
    }
#pragma unroll
    for (int off = 8; off; off >>= 1) Z += __shfl_xor(Z, off);
    float invZ = 1.f / Z;

    const char* Wp = (const char*)(Who + (size_t)b * N * HH);
    int lane4 = sub << 4;
    float4 acc = make_float4(0.f, 0.f, 0.f, 0.f);
    int e = 0;
    for (; e + 2 <= c; e += 2) {
        float2 p0 = sedge[r][e];
        float2 p1 = sedge[r][e + 1];
        float4 v0 = *(const float4*)(Wp + (__float_as_int(p0.x) + lane4));
        float4 v1 = *(const float4*)(Wp + (__float_as_int(p1.x) + lane4));
        acc.x += p0.y * v0.x; acc.y += p0.y * v0.y;
        acc.z += p0.y * v0.z; acc.w += p0.y * v0.w;
        acc.x += p1.y * v1.x; acc.y += p1.y * v1.y;
        acc.z += p1.y * v1.z; acc.w += p1.y * v1.w;
    }
    if (e < c) {
        float2 p0 = sedge[r][e];
        float4 v0 = *(const float4*)(Wp + (__float_as_int(p0.x) + lane4));
        acc.x += p0.y * v0.x; acc.y += p0.y * v0.y;
        acc.z += p0.y * v0.z; acc.w += p0.y * v0.w;
    }
    float4 o;
    o.x = elu1(acc.x * invZ); o.y = elu1(acc.y * invZ);
    o.z = elu1(acc.z * invZ); o.w = elu1(acc.w * invZ);
    *(float4*)&out[(size_t)(b * N + i) * HH + sub * 4] = o;
}

// ---------------------------------------------------------------------------
extern "C" void kernel_launch(void* const* d_in, const int* in_sizes, int n_in,
                              void* d_out, int out_size, void* d_ws, size_t ws_size,
                              hipStream_t stream) {
    const float* inp   = (const float*)d_in[0];
    const float* envs  = (const float*)d_in[1];
    const float* st    = (const float*)d_in[2];
    const float* bias  = (const float*)d_in[3];
    const float* W_h   = (const float*)d_in[4];
    const float* a1_h  = (const float*)d_in[5];
    const float* a2_h  = (const float*)d_in[6];
    const float* W_o   = (const float*)d_in[7];
    const float* a1_o  = (const float*)d_in[8];
    const float* a2_o  = (const float*)d_in[9];
    float* out = (float*)d_out;

    char* ws = (char*)d_ws;
    size_t off = 0;
    __hip_bfloat16* Whb = (__hip_bfloat16*)(ws + off); off += (size_t)B * KK * N * HH * 2; // 16.8 MB
    float* f1  = (float*)(ws + off); off += (size_t)B * KK * N * 4;        // 0.5 MB
    float* f2  = (float*)(ws + off); off += (size_t)B * KK * N * 4;        // 0.5 MB
    float* h1  = (float*)(ws + off); off += (size_t)B * N * KK * HH * 4;   // 33.5 MB
    float* Who = (float*)(ws + off); off += (size_t)B * N * HH * 4;        // 4 MB
    float* f1o = (float*)(ws + off); off += (size_t)B * N * 4;
    float* f2o = (float*)(ws + off); off += (size_t)B * N * 4;
    int*   cols = (int*)(ws + off);  off += (size_t)N * CAP * 4;           // 3 MB
    int*   cnt  = (int*)(ws + off);  off += (size_t)N * 4;

    k_mask<<<dim3(N), dim3(64), 0, stream>>>(bias, cols, cnt);
    k_wh<<<dim3(N / 128, KK, B), dim3(256), 0, stream>>>(inp, envs, st, W_h, a1_h, a2_h,
                                                         Whb, f1, f2);
    k_attn<<<dim3(N / 16, B * KK), dim3(256), 0, stream>>>(Whb, f1, f2, cols, cnt, h1);
    k_who<<<dim3(B * N / 16), dim3(256), 0, stream>>>(h1, W_o, a1_o, a2_o, Who, f1o, f2o);
    k_attn2<<<dim3(N / 16, B), dim3(256), 0, stream>>>(Who, f1o, f2o, cols, cnt, out);
}

// Round 5
// 315.224 us; speedup vs baseline: 2.5776x; 1.3967x over previous
//
#include <hip/hip_runtime.h>
#include <hip/hip_bf16.h>
#include <math.h>

#define B   8
#define N   2048
#define DIN 2
#define DF  30
#define HH  64
#define KK  8
#define DATT 96          // DIN + DF + HH
#define CAP 384          // global ELL cap (~103 avg, huge margin)
#define CAPL 176         // LDS edge cap (passed twice; dataset max <= 176)
#define ALPHA 0.2f

__device__ __forceinline__ float lrelu(float x) { return x > 0.f ? x : ALPHA * x; }
__device__ __forceinline__ float elu1(float x)  { return x > 0.f ? x : (__expf(x) - 1.f); }
__device__ __forceinline__ unsigned short f2bf(float x) {
    __hip_bfloat16 h = __float2bfloat16(x);
    return *reinterpret_cast<unsigned short*>(&h);
}

// ---------------------------------------------------------------------------
// Kernel B: bias_mat (0 / -1e9) -> padded ELL  (cols[i*CAP + e], cnt[i])
// ---------------------------------------------------------------------------
__global__ void k_mask(const float* __restrict__ bias, int* __restrict__ cols,
                       int* __restrict__ cnt) {
    int i = blockIdx.x;
    int lane = threadIdx.x;
    int c = 0;
    for (int j0 = 0; j0 < N; j0 += 64) {
        float v = bias[(size_t)i * N + j0 + lane];
        bool conn = v > -1e8f;
        unsigned long long m = __ballot(conn);
        if (conn) {
            int pos = c + __popcll(m & ((1ull << lane) - 1ull));
            if (pos < CAP) cols[i * CAP + pos] = j0 + lane;
        }
        c += __popcll(m);
    }
    if (lane == 0) cnt[i] = c < CAP ? c : CAP;
}

// ---------------------------------------------------------------------------
// Kernel A v2: Whb (bf16) = h @ W_h[k];  f1/f2 f32.
// 16 rows/block computed in PARALLEL: 16-lane group per row, 4 ch/lane.
// h-tile (16 x 96, stride 98) + W_h[k] (24 KB) staged in LDS.
// grid = (N/16, K, B), block 256.
// ---------------------------------------------------------------------------
__global__ void k_wh(const float* __restrict__ inp, const float* __restrict__ envs,
                     const float* __restrict__ st,  const float* __restrict__ W_h,
                     const float* __restrict__ a1,  const float* __restrict__ a2,
                     __hip_bfloat16* __restrict__ Whb,
                     float* __restrict__ f1, float* __restrict__ f2) {
    __shared__ float Ws[DATT * HH];    // 24576 B
    __shared__ float hs[16 * 98];      // 6272 B  (row stride 98: b64-aligned pairs, bank-spread)
    int k = blockIdx.y, b = blockIdx.z;
    int i0 = blockIdx.x * 16;
    int tid = threadIdx.x, lane = tid & 63, w = tid >> 6;
    int g = lane >> 4, sub = lane & 15;
    int r = w * 4 + g;

    // stage W_h[k]
    const float* Wk = W_h + k * DATT * HH;
    for (int idx = tid * 4; idx < DATT * HH; idx += 1024)
        *(float4*)&Ws[idx] = *(const float4*)&Wk[idx];
    // stage h-tile: concat layout [inp(2) | envs(30) | st(64)]
    {
        int row = tid >> 4, q = tid & 15;           // st: 16 rows x 16 float4
        float4 v = *(const float4*)&st[(size_t)(b * N + i0 + row) * HH + q * 4];
        float* hb = &hs[row * 98 + DIN + DF + q * 4];
        hb[0] = v.x; hb[1] = v.y; hb[2] = v.z; hb[3] = v.w;
    }
    if (tid < 240) {                                 // envs: 16 rows x 15 float2
        int row = tid / 15, q = tid % 15;
        float2 v = *(const float2*)&envs[(size_t)(b * N + i0 + row) * DF + q * 2];
        float* hb = &hs[row * 98 + DIN + q * 2];
        hb[0] = v.x; hb[1] = v.y;
    }
    if (tid < 32) {                                  // inp: 16 rows x 2
        int row = tid >> 1, q = tid & 1;
        hs[row * 98 + q] = inp[(size_t)(b * N + i0 + row) * DIN + q];
    }
    __syncthreads();

    const float* hb = &hs[r * 98];
    float4 acc = make_float4(0.f, 0.f, 0.f, 0.f);
#pragma unroll
    for (int d = 0; d < DATT; d += 2) {
        float2 hv = *(const float2*)&hb[d];
        float4 w0 = *(const float4*)&Ws[d * HH + sub * 4];
        float4 w1 = *(const float4*)&Ws[(d + 1) * HH + sub * 4];
        acc.x += hv.x * w0.x; acc.y += hv.x * w0.y;
        acc.z += hv.x * w0.z; acc.w += hv.x * w0.w;
        acc.x += hv.y * w1.x; acc.y += hv.y * w1.y;
        acc.z += hv.y * w1.z; acc.w += hv.y * w1.w;
    }
    int i = i0 + r;
    int bkN = (b * KK + k) * N;
    // bf16 pack + store (8 B per lane, channels sub*4..sub*4+3)
    unsigned int lo = (unsigned)f2bf(acc.x) | ((unsigned)f2bf(acc.y) << 16);
    unsigned int hi = (unsigned)f2bf(acc.z) | ((unsigned)f2bf(acc.w) << 16);
    *(uint2*)&Whb[((size_t)bkN + i) * HH + sub * 4] = make_uint2(lo, hi);
    // f1/f2
    float4 a1v = *(const float4*)&a1[k * HH + sub * 4];
    float4 a2v = *(const float4*)&a2[k * HH + sub * 4];
    float p1 = acc.x * a1v.x + acc.y * a1v.y + acc.z * a1v.z + acc.w * a1v.w;
    float p2 = acc.x * a2v.x + acc.y * a2v.y + acc.z * a2v.z + acc.w * a2v.w;
#pragma unroll
    for (int off = 8; off; off >>= 1) {
        p1 += __shfl_xor(p1, off);
        p2 += __shfl_xor(p2, off);
    }
    if (sub == 0) { f1[bkN + i] = p1; f2[bkN + i] = p2; }
}

// ---------------------------------------------------------------------------
// Kernel C v3: sparse softmax-attention, multihead, bf16 gather.
// XCD-swizzled so each XCD owns 8 contiguous bk values (Wh slab L2-resident).
// No f2 LDS staging (8 KB slab is L1-resident). Gather unrolled 4x.
// grid = (N/16, B*K), block 256.
// ---------------------------------------------------------------------------
__global__ void k_attn(const __hip_bfloat16* __restrict__ Whb, const float* __restrict__ f1,
                       const float* __restrict__ f2, const int* __restrict__ cols,
                       const int* __restrict__ cnt, float* __restrict__ h1) {
    __shared__ float2 sedge[16][CAPL + 2];     // 22.8 KB
    // bijective XCD swizzle: flat -> (bk, tile); xcd = flat%8 owns bk in [xcd*8, xcd*8+8)
    int flat = blockIdx.y * 128 + blockIdx.x;
    int xcd = flat & 7, sq = flat >> 3;
    int bk = (xcd << 3) | (sq >> 7);
    int tile = sq & 127;
    int b = bk >> 3, k = bk & 7;
    int tid = threadIdx.x;
    int lane = tid & 63, w = tid >> 6;
    int g = lane >> 4, sub = lane & 15;
    int r = w * 4 + g;
    int i = tile * 16 + r;

    int c = cnt[i]; if (c > CAPL) c = CAPL;
    float f1i = f1[bk * N + i];
    const int* cl = cols + (size_t)i * CAP;
    const float* f2p = f2 + bk * N;

    // pass A: scores + byte offsets (row stride 128 B), row max (16-lane parallel)
    float m = -1e30f;
    for (int e = sub; e < c; e += 16) {
        int j = cl[e];
        float sc = lrelu(f1i + f2p[j]);
        sedge[r][e] = make_float2(__int_as_float(j << 7), sc);
        m = fmaxf(m, sc);
    }
#pragma unroll
    for (int off = 8; off; off >>= 1) m = fmaxf(m, __shfl_xor(m, off));

    // pass B: exp + Z
    float Z = 0.f;
    for (int e = sub; e < c; e += 16) {
        float wt = __expf(sedge[r][e].y - m);
        sedge[r][e].y = wt;
        Z += wt;
    }
#pragma unroll
    for (int off = 8; off; off >>= 1) Z += __shfl_xor(Z, off);
    float invZ = 1.f / Z;

    // pass C: gather-FMA, bf16 rows, 4 ch/lane, unroll 4 (4 loads in flight)
    const char* Whp = (const char*)(Whb + (size_t)bk * N * HH);
    int lane8 = sub << 3;
    float4 acc = make_float4(0.f, 0.f, 0.f, 0.f);
    int e = 0;
    for (; e + 4 <= c; e += 4) {
        float2 p0 = sedge[r][e];
        float2 p1 = sedge[r][e + 1];
        float2 p2 = sedge[r][e + 2];
        float2 p3 = sedge[r][e + 3];
        uint2 v0 = *(const uint2*)(Whp + (__float_as_int(p0.x) + lane8));
        uint2 v1 = *(const uint2*)(Whp + (__float_as_int(p1.x) + lane8));
        uint2 v2 = *(const uint2*)(Whp + (__float_as_int(p2.x) + lane8));
        uint2 v3 = *(const uint2*)(Whp + (__float_as_int(p3.x) + lane8));
        acc.x += p0.y * __int_as_float(v0.x << 16);
        acc.y += p0.y * __int_as_float(v0.x & 0xffff0000u);
        acc.z += p0.y * __int_as_float(v0.y << 16);
        acc.w += p0.y * __int_as_float(v0.y & 0xffff0000u);
        acc.x += p1.y * __int_as_float(v1.x << 16);
        acc.y += p1.y * __int_as_float(v1.x & 0xffff0000u);
        acc.z += p1.y * __int_as_float(v1.y << 16);
        acc.w += p1.y * __int_as_float(v1.y & 0xffff0000u);
        acc.x += p2.y * __int_as_float(v2.x << 16);
        acc.y += p2.y * __int_as_float(v2.x & 0xffff0000u);
        acc.z += p2.y * __int_as_float(v2.y << 16);
        acc.w += p2.y * __int_as_float(v2.y & 0xffff0000u);
        acc.x += p3.y * __int_as_float(v3.x << 16);
        acc.y += p3.y * __int_as_float(v3.x & 0xffff0000u);
        acc.z += p3.y * __int_as_float(v3.y << 16);
        acc.w += p3.y * __int_as_float(v3.y & 0xffff0000u);
    }
    for (; e < c; ++e) {
        float2 p0 = sedge[r][e];
        uint2 v0 = *(const uint2*)(Whp + (__float_as_int(p0.x) + lane8));
        acc.x += p0.y * __int_as_float(v0.x << 16);
        acc.y += p0.y * __int_as_float(v0.x & 0xffff0000u);
        acc.z += p0.y * __int_as_float(v0.y << 16);
        acc.w += p0.y * __int_as_float(v0.y & 0xffff0000u);
    }
    float4 o;
    o.x = elu1(acc.x * invZ); o.y = elu1(acc.y * invZ);
    o.z = elu1(acc.z * invZ); o.w = elu1(acc.w * invZ);
    *(float4*)&h1[(size_t)(b * N + i) * (KK * HH) + k * HH + sub * 4] = o;
}

// ---------------------------------------------------------------------------
// Kernel D: Who = h1 @ W_o (512 -> 64) + f1o/f2o.
// 1024 blocks, 16 rows/block, 4 rows/wave, W_o in 4 x 32KB LDS phases.
// ---------------------------------------------------------------------------
__global__ void k_who(const float* __restrict__ h1, const float* __restrict__ W_o,
                      const float* __restrict__ a1o, const float* __restrict__ a2o,
                      float* __restrict__ Who, float* __restrict__ f1o,
                      float* __restrict__ f2o) {
    __shared__ float Ws[128 * HH];             // 32 KB
    int tid = threadIdx.x, lane = tid & 63, w = tid >> 6;
    int g = lane >> 4, sub = lane & 15;
    int row = blockIdx.x * 16 + w * 4 + g;
    const float* hp = h1 + (size_t)row * (KK * HH);
    float4 acc = make_float4(0.f, 0.f, 0.f, 0.f);
    for (int ph = 0; ph < 4; ++ph) {
        __syncthreads();
        for (int idx = tid * 4; idx < 128 * HH; idx += 1024)
            *(float4*)&Ws[idx] = *(const float4*)&W_o[ph * 128 * HH + idx];
        __syncthreads();
#pragma unroll 4
        for (int d0 = 0; d0 < 128; d0 += 4) {
            float4 hv = *(const float4*)(hp + ph * 128 + d0);
#pragma unroll
            for (int dd = 0; dd < 4; ++dd) {
                float hsv = dd == 0 ? hv.x : dd == 1 ? hv.y : dd == 2 ? hv.z : hv.w;
                float4 wv = *(const float4*)&Ws[(d0 + dd) * HH + sub * 4];
                acc.x += hsv * wv.x; acc.y += hsv * wv.y;
                acc.z += hsv * wv.z; acc.w += hsv * wv.w;
            }
        }
    }
    *(float4*)&Who[(size_t)row * HH + sub * 4] = acc;
    float4 a1v = *(const float4*)&a1o[sub * 4];
    float4 a2v = *(const float4*)&a2o[sub * 4];
    float p1 = acc.x * a1v.x + acc.y * a1v.y + acc.z * a1v.z + acc.w * a1v.w;
    float p2 = acc.x * a2v.x + acc.y * a2v.y + acc.z * a2v.z + acc.w * a2v.w;
#pragma unroll
    for (int off = 8; off; off >>= 1) {
        p1 += __shfl_xor(p1, off);
        p2 += __shfl_xor(p2, off);
    }
    if (sub == 0) { f1o[row] = p1; f2o[row] = p2; }
}

// ---------------------------------------------------------------------------
// Kernel E v3: second sparse attention + final elu -> out (f32 gather).
// XCD swizzle: each XCD owns one b (512 KB slab L2-resident). Unroll 4.
// grid = (N/16, B), block 256.
// ---------------------------------------------------------------------------
__global__ void k_attn2(const float* __restrict__ Who, const float* __restrict__ f1o,
                        const float* __restrict__ f2o, const int* __restrict__ cols,
                        const int* __restrict__ cnt, float* __restrict__ out) {
    __shared__ float2 sedge[16][CAPL + 2];
    int flat = blockIdx.y * 128 + blockIdx.x;
    int b = flat & 7;
    int tile = flat >> 3;
    int tid = threadIdx.x;
    int lane = tid & 63, w = tid >> 6;
    int g = lane >> 4, sub = lane & 15;
    int r = w * 4 + g;
    int i = tile * 16 + r;

    int c = cnt[i]; if (c > CAPL) c = CAPL;
    float f1i = f1o[b * N + i];
    const int* cl = cols + (size_t)i * CAP;
    const float* f2p = f2o + b * N;

    float m = -1e30f;
    for (int e = sub; e < c; e += 16) {
        int j = cl[e];
        float sc = lrelu(f1i + f2p[j]);
        sedge[r][e] = make_float2(__int_as_float(j << 8), sc);
        m = fmaxf(m, sc);
    }
#pragma unroll
    for (int off = 8; off; off >>= 1) m = fmaxf(m, __shfl_xor(m, off));

    float Z = 0.f;
    for (int e = sub; e < c; e += 16) {
        float wt = __expf(sedge[r][e].y - m);
        sedge[r][e].y = wt;
        Z += wt;
    }
#pragma unroll
    for (int off = 8; off; off >>= 1) Z += __shfl_xor(Z, off);
    float invZ = 1.f / Z;

    const char* Wp = (const char*)(Who + (size_t)b * N * HH);
    int lane4 = sub << 4;
    float4 acc = make_float4(0.f, 0.f, 0.f, 0.f);
    int e = 0;
    for (; e + 4 <= c; e += 4) {
        float2 p0 = sedge[r][e];
        float2 p1 = sedge[r][e + 1];
        float2 p2 = sedge[r][e + 2];
        float2 p3 = sedge[r][e + 3];
        float4 v0 = *(const float4*)(Wp + (__float_as_int(p0.x) + lane4));
        float4 v1 = *(const float4*)(Wp + (__float_as_int(p1.x) + lane4));
        float4 v2 = *(const float4*)(Wp + (__float_as_int(p2.x) + lane4));
        float4 v3 = *(const float4*)(Wp + (__float_as_int(p3.x) + lane4));
        acc.x += p0.y * v0.x; acc.y += p0.y * v0.y;
        acc.z += p0.y * v0.z; acc.w += p0.y * v0.w;
        acc.x += p1.y * v1.x; acc.y += p1.y * v1.y;
        acc.z += p1.y * v1.z; acc.w += p1.y * v1.w;
        acc.x += p2.y * v2.x; acc.y += p2.y * v2.y;
        acc.z += p2.y * v2.z; acc.w += p2.y * v2.w;
        acc.x += p3.y * v3.x; acc.y += p3.y * v3.y;
        acc.z += p3.y * v3.z; acc.w += p3.y * v3.w;
    }
    for (; e < c; ++e) {
        float2 p0 = sedge[r][e];
        float4 v0 = *(const float4*)(Wp + (__float_as_int(p0.x) + lane4));
        acc.x += p0.y * v0.x; acc.y += p0.y * v0.y;
        acc.z += p0.y * v0.z; acc.w += p0.y * v0.w;
    }
    float4 o;
    o.x = elu1(acc.x * invZ); o.y = elu1(acc.y * invZ);
    o.z = elu1(acc.z * invZ); o.w = elu1(acc.w * invZ);
    *(float4*)&out[(size_t)(b * N + i) * HH + sub * 4] = o;
}

// ---------------------------------------------------------------------------
extern "C" void kernel_launch(void* const* d_in, const int* in_sizes, int n_in,
                              void* d_out, int out_size, void* d_ws, size_t ws_size,
                              hipStream_t stream) {
    const float* inp   = (const float*)d_in[0];
    const float* envs  = (const float*)d_in[1];
    const float* st    = (const float*)d_in[2];
    const float* bias  = (const float*)d_in[3];
    const float* W_h   = (const float*)d_in[4];
    const float* a1_h  = (const float*)d_in[5];
    const float* a2_h  = (const float*)d_in[6];
    const float* W_o   = (const float*)d_in[7];
    const float* a1_o  = (const float*)d_in[8];
    const float* a2_o  = (const float*)d_in[9];
    float* out = (float*)d_out;

    char* ws = (char*)d_ws;
    size_t off = 0;
    __hip_bfloat16* Whb = (__hip_bfloat16*)(ws + off); off += (size_t)B * KK * N * HH * 2; // 16.8 MB
    float* f1  = (float*)(ws + off); off += (size_t)B * KK * N * 4;        // 0.5 MB
    float* f2  = (float*)(ws + off); off += (size_t)B * KK * N * 4;        // 0.5 MB
    float* h1  = (float*)(ws + off); off += (size_t)B * N * KK * HH * 4;   // 33.5 MB
    float* Who = (float*)(ws + off); off += (size_t)B * N * HH * 4;        // 4 MB
    float* f1o = (float*)(ws + off); off += (size_t)B * N * 4;
    float* f2o = (float*)(ws + off); off += (size_t)B * N * 4;
    int*   cols = (int*)(ws + off);  off += (size_t)N * CAP * 4;           // 3 MB
    int*   cnt  = (int*)(ws + off);  off += (size_t)N * 4;

    k_mask<<<dim3(N), dim3(64), 0, stream>>>(bias, cols, cnt);
    k_wh<<<dim3(N / 16, KK, B), dim3(256), 0, stream>>>(inp, envs, st, W_h, a1_h, a2_h,
                                                        Whb, f1, f2);
    k_attn<<<dim3(N / 16, B * KK), dim3(256), 0, stream>>>(Whb, f1, f2, cols, cnt, h1);
    k_who<<<dim3(B * N / 16), dim3(256), 0, stream>>>(h1, W_o, a1_o, a2_o, Who, f1o, f2o);
    k_attn2<<<dim3(N / 16, B), dim3(256), 0, stream>>>(Who, f1o, f2o, cols, cnt, out);
}